// Round 15
// baseline (475.251 us; speedup 1.0000x reference)
//
#include <hip/hip_runtime.h>
#include <hip/hip_bf16.h>

// Geo2Vec fused MLP, bf16 MFMA. Round 15: R14 + deeper register pipelines.
// At 512 thr / 1 block/CU the VGPR cap is 256 (2 waves/SIMD); R14 used 88.
// A: 3 buffers (2-ahead, ~80-160cy lead >= 120cy ds_read latency).
// B: 4 buffers (3-ahead, ~120-240cy lead >= 200cy L2 latency).

typedef __attribute__((ext_vector_type(8))) __bf16 bfv8;
typedef __attribute__((ext_vector_type(8))) short s16x8;
typedef __attribute__((ext_vector_type(4))) float f32x4;
typedef __attribute__((ext_vector_type(4))) int i32x4;

__device__ __forceinline__ short f2bf(float f) {
  unsigned u = __builtin_bit_cast(unsigned, f);
  u = (u + 0x7fffu + ((u >> 16) & 1u)) >> 16;
  return (short)u;
}
__device__ __forceinline__ float bf2f(short s) {
  unsigned u = ((unsigned)(unsigned short)s) << 16;
  return __builtin_bit_cast(float, u);
}
__device__ __forceinline__ int swzaddr(int base, int stride, int row, int colbyte) {
  return base + row * stride + (colbyte ^ (((row & 7) << 4) ^ ((row & 8) << 2)));
}
// LDS-visibility barrier that does NOT drain vmcnt (keeps B prefetch in flight).
__device__ __forceinline__ void ldsbar() {
  __builtin_amdgcn_sched_barrier(0);
  asm volatile("s_waitcnt lgkmcnt(0)");
  __builtin_amdgcn_s_barrier();
  __builtin_amdgcn_sched_barrier(0);
}

// ---------------- weight pack ----------------
// fp32 row-major (K,256) -> bf16 B-frag-major with INTERLEAVED columns:
// packet p = (kt*16 + nt)*64 + lane ; frag col j=lane&15 -> actual col
// n = (nt>>1)*32 + 2*j + (nt&1)   (epilogue cvt_pk un-interleaves)
__global__ void pack_weights_kernel(const float* __restrict__ W1a, const float* __restrict__ W1b,
                                    const float* __restrict__ Wa, const float* __restrict__ Wb,
                                    short* __restrict__ ws) {
  int p = blockIdx.x * blockDim.x + threadIdx.x;
  const int P1 = 10240;           // W1a: 10 kt * 16 nt * 64
  const int P2 = P1 + 8192;       // W1b
  const int P3 = P2 + 8 * 18432;  // Wa
  const int P4 = P3 + 8 * 8192;   // Wb
  if (p >= P4) return;
  const float* src;
  int q;
  if (p < P1)      { src = W1a; q = p; }
  else if (p < P2) { src = W1b; q = p - P1; }
  else if (p < P3) { q = p - P2; int l = q / 18432; q -= l * 18432; src = Wa + l * 147456; }
  else             { q = p - P3; int l = q / 8192;  q -= l * 8192;  src = Wb + l * 65536; }
  const int lane = q & 63, t = q >> 6, nt = t & 15, kt = t >> 4;
  const int k0 = kt * 32 + ((lane >> 4) << 3);
  const int n  = ((nt >> 1) << 5) + ((lane & 15) << 1) + (nt & 1);
  short* dst = ws + (size_t)p * 8;
#pragma unroll
  for (int i = 0; i < 8; ++i) dst[i] = f2bf(src[(size_t)(k0 + i) * 256 + n]);
}

// ---------------- fused MLP ----------------
// LDS (bytes): xyz [0,40960) stride 640 ; x [40960,73728) stride 512 ;
//              t [73728,106496) stride 512
struct BPre { bfv8 b0, b1; };
struct AFrag { bfv8 r0, r1, r2, r3; };

__device__ __forceinline__ bfv8 bfrag(const short* __restrict__ wp, int kt, int nt, int lane) {
  const short* base = wp + (((size_t)(kt * 16 + nt)) << 9);  // wave-uniform
  return *(const bfv8*)(base + (lane << 3));
}

template<int NKT, int SPLITKT, bool LEAKY>
__device__ __forceinline__ BPre do_gemm(short* lds,
    int a1Base, int a1S, int a2Base, int a2S,
    const short* __restrict__ wp, const short* __restrict__ wpn,
    const float* __restrict__ bias, int outBase,
    int wc, int lane, BPre pre)
{
  const int lo = lane & 15, hi = lane >> 4;
  const int ntb = wc << 1;
  const float2 bv = *(const float2*)(bias + (wc << 5) + (lo << 1));
  f32x4 acc[4][2];
#pragma unroll
  for (int r = 0; r < 4; ++r) { acc[r][0] = (f32x4)0.f; acc[r][1] = (f32x4)0.f; }

  // Decomposed swizzle bases: addr = base[kk&1] + (kk>>1)*128 + rt*(stride*16)
  const int xr  = ((lo & 7) << 4) ^ ((lo & 8) << 2);
  const int hib = hi << 4;
  const char* A1E = (const char*)lds + a1Base + lo * a1S + ((     hib) ^ xr);
  const char* A1O = (const char*)lds + a1Base + lo * a1S + ((64 + hib) ^ xr);
  const char* A2E = (const char*)lds + a2Base + lo * a2S + ((     hib) ^ xr);
  const char* A2O = (const char*)lds + a2Base + lo * a2S + ((64 + hib) ^ xr);

  // A loader (static kt after unroll)
  auto aLoad = [&](int kt, AFrag& dst) {
    const bool g1 = kt < SPLITKT;
    const int kk  = g1 ? kt : kt - SPLITKT;
    const int st  = g1 ? a1S : a2S;
    const char* b = (g1 ? ((kk & 1) ? A1O : A1E) : ((kk & 1) ? A2O : A2E)) + (kk >> 1) * 128;
    dst.r0 = *(const bfv8*)(b);
    dst.r1 = *(const bfv8*)(b + (st << 4));
    dst.r2 = *(const bfv8*)(b + (st << 5));
    dst.r3 = *(const bfv8*)(b + (st << 4) * 3);
  };

  bfv8 bst[4][2];
  AFrag ast[3];
  bst[0][0] = pre.b0; bst[0][1] = pre.b1;
  if (NKT > 1) { bst[1][0] = bfrag(wp, 1, ntb, lane); bst[1][1] = bfrag(wp, 1, ntb + 1, lane); }
  if (NKT > 2) { bst[2][0] = bfrag(wp, 2, ntb, lane); bst[2][1] = bfrag(wp, 2, ntb + 1, lane); }
  aLoad(0, ast[0]);
  if (NKT > 1) aLoad(1, ast[1]);
  BPre nxt;

#pragma unroll
  for (int i = 0; i < NKT; ++i) {
    if (i + 3 < NKT) {
      bst[(i + 3) & 3][0] = bfrag(wp, i + 3, ntb, lane);
      bst[(i + 3) & 3][1] = bfrag(wp, i + 3, ntb + 1, lane);
    } else if (i + 3 == NKT || (NKT <= 3 && i == 0)) {  // next gemm's first B frags
      nxt.b0 = bfrag(wpn, 0, ntb, lane);
      nxt.b1 = bfrag(wpn, 0, ntb + 1, lane);
    }
    if (i + 2 < NKT) aLoad(i + 2, ast[(i + 2) % 3]);
    const AFrag& ac = ast[i % 3];
    __builtin_amdgcn_s_setprio(1);
    acc[0][0] = __builtin_amdgcn_mfma_f32_16x16x32_bf16(ac.r0, bst[i & 3][0], acc[0][0], 0, 0, 0);
    acc[0][1] = __builtin_amdgcn_mfma_f32_16x16x32_bf16(ac.r0, bst[i & 3][1], acc[0][1], 0, 0, 0);
    acc[1][0] = __builtin_amdgcn_mfma_f32_16x16x32_bf16(ac.r1, bst[i & 3][0], acc[1][0], 0, 0, 0);
    acc[1][1] = __builtin_amdgcn_mfma_f32_16x16x32_bf16(ac.r1, bst[i & 3][1], acc[1][1], 0, 0, 0);
    acc[2][0] = __builtin_amdgcn_mfma_f32_16x16x32_bf16(ac.r2, bst[i & 3][0], acc[2][0], 0, 0, 0);
    acc[2][1] = __builtin_amdgcn_mfma_f32_16x16x32_bf16(ac.r2, bst[i & 3][1], acc[2][1], 0, 0, 0);
    acc[3][0] = __builtin_amdgcn_mfma_f32_16x16x32_bf16(ac.r3, bst[i & 3][0], acc[3][0], 0, 0, 0);
    acc[3][1] = __builtin_amdgcn_mfma_f32_16x16x32_bf16(ac.r3, bst[i & 3][1], acc[3][1], 0, 0, 0);
    __builtin_amdgcn_s_setprio(0);
  }
  // epilogue: bias + leaky + cvt_pk(2 bf16) -> one b32 store per pair
#pragma unroll
  for (int rt = 0; rt < 4; ++rt)
#pragma unroll
    for (int rr = 0; rr < 4; ++rr) {
      float v0 = acc[rt][0][rr] + bv.x;
      float v1 = acc[rt][1][rr] + bv.y;
      if (LEAKY) { v0 = fmaxf(v0, 0.01f * v0); v1 = fmaxf(v1, 0.01f * v1); }
      unsigned pk;
      asm("v_cvt_pk_bf16_f32 %0, %1, %2" : "=v"(pk) : "v"(v0), "v"(v1));
      const int orow = (rt << 4) + (hi << 2) + rr;
      *(unsigned*)((char*)lds + swzaddr(outBase, 512, orow, (wc << 6) + (lo << 2))) = pk;
    }
  return nxt;
}

__launch_bounds__(512, 1)
__global__ void geo2vec_kernel(const float* __restrict__ xy, const int* __restrict__ idx,
    const float* __restrict__ emb,
    const float* __restrict__ b1a, const float* __restrict__ b1b,
    const float* __restrict__ ba, const float* __restrict__ bb,
    const float* __restrict__ W2, const float* __restrict__ b2,
    const short* __restrict__ wp, float* __restrict__ out)
{
  __shared__ short lds[53248];  // 104 KB
  const int tid = threadIdx.x;
  const int lane = tid & 63;
  const int wc = __builtin_amdgcn_readfirstlane(tid >> 6);  // wave = col group

  // issue first gemm's B stage-0 loads immediately: hide under prologue trig
  BPre pre;
  pre.b0 = bfrag(wp, 0, (wc << 1), lane);
  pre.b1 = bfrag(wp, 0, (wc << 1) + 1, lane);

  // ---- prologue: pos-encode + gather z -> xyz tile (64 x 320 bf16) ----
  {
    const int g = tid >> 3, j = tid & 7;  // 8 threads per row
    const int row = blockIdx.x * 64 + g;
    const float xv = xy[2 * row], yv = xy[2 * row + 1];
    const float rv = sqrtf(xv * xv + yv * yv);
    union { short s[8]; i32x4 v; } tmp;
#pragma unroll
    for (int i = 0; i < 8; ++i) {
      const int c = 8 * j + i;
      float fv;
      if (c < 2)       fv = c ? yv : xv;
      else if (c < 22) { int m = c - 2;  float f = 1.0f + (5.0f / 9.0f) * (m >> 1); fv = sinf(((m & 1) ? yv : xv) * f); }
      else if (c < 42) { int m = c - 22; float f = 1.0f + (5.0f / 9.0f) * (m >> 1); fv = cosf(((m & 1) ? yv : xv) * f); }
      else if (c < 44) fv = (c == 42) ? xv : yv;
      else if (c < 54) fv = sinf(rv * (1.0f + (5.0f / 9.0f) * (c - 44)));
      else             fv = cosf(rv * (1.0f + (5.0f / 9.0f) * (c - 54)));
      tmp.s[i] = f2bf(fv);
    }
    *(i32x4*)((char*)lds + swzaddr(0, 640, g, j << 4)) = tmp.v;
    const float* zr = emb + (size_t)(unsigned)idx[row] * 256;
#pragma unroll
    for (int c4 = 0; c4 < 4; ++c4) {
      const int cel = j * 32 + c4 * 8;
      const float4 f0 = *(const float4*)(zr + cel);
      const float4 f1 = *(const float4*)(zr + cel + 4);
      union { short s[8]; i32x4 v; } t2;
      t2.s[0] = f2bf(f0.x); t2.s[1] = f2bf(f0.y); t2.s[2] = f2bf(f0.z); t2.s[3] = f2bf(f0.w);
      t2.s[4] = f2bf(f1.x); t2.s[5] = f2bf(f1.y); t2.s[6] = f2bf(f1.z); t2.s[7] = f2bf(f1.w);
      *(i32x4*)((char*)lds + swzaddr(0, 640, g, (64 + cel) << 1)) = t2.v;
    }
  }
  ldsbar();

  // layer 1
  pre = do_gemm<10, 10, true >(lds, 0, 640, 0, 640,         wp,         wp + 81920,  b1a, 73728, wc, lane, pre);
  ldsbar();
  pre = do_gemm<8,  8,  false>(lds, 73728, 512, 73728, 512, wp + 81920, wp + 147456, b1b, 40960, wc, lane, pre);
  ldsbar();
  // 8 mid layers
  for (int l = 0; l < 8; ++l) {
    const short* wa = wp + 147456 + l * 147456;
    const short* wb = wp + 1327104 + l * 65536;
    const short* wan = (l < 7) ? (wa + 147456) : wp;  // dummy (valid mem) on last layer
    pre = do_gemm<18, 10, true >(lds, 0, 640, 40960, 512,     wa, wb,  ba + l * 256, 73728, wc, lane, pre);
    ldsbar();
    pre = do_gemm<8,  8,  false>(lds, 73728, 512, 73728, 512, wb, wan, bb + l * 256, 40960, wc, lane, pre);
    ldsbar();
  }
  // final: out = x @ W2 + b2 ; 8 threads per row (32 cols each), width-8 reduce
  {
    const int r = tid >> 3, j = tid & 7;
    float sum = 0.f;
#pragma unroll
    for (int h = 0; h < 4; ++h) {
      const int cb = 64 * j + 16 * h;
      const s16x8 v = *(const s16x8*)((const char*)lds + swzaddr(40960, 512, r, cb));
      const int c0 = 32 * j + 8 * h;
      const float4 w0 = *(const float4*)(W2 + c0);
      const float4 w1 = *(const float4*)(W2 + c0 + 4);
      sum += bf2f(v[0]) * w0.x + bf2f(v[1]) * w0.y + bf2f(v[2]) * w0.z + bf2f(v[3]) * w0.w;
      sum += bf2f(v[4]) * w1.x + bf2f(v[5]) * w1.y + bf2f(v[6]) * w1.z + bf2f(v[7]) * w1.w;
    }
    sum += __shfl_xor(sum, 1); sum += __shfl_xor(sum, 2); sum += __shfl_xor(sum, 4);
    if (j == 0) out[blockIdx.x * 64 + r] = sum + b2[0];
  }
}

extern "C" void kernel_launch(void* const* d_in, const int* in_sizes, int n_in,
                              void* d_out, int out_size, void* d_ws, size_t ws_size,
                              hipStream_t stream) {
  const float* xy  = (const float*)d_in[0];
  const int*   idx = (const int*)d_in[1];
  const float* emb = (const float*)d_in[2];
  const float* W1a = (const float*)d_in[3];
  const float* b1a = (const float*)d_in[4];
  const float* W1b = (const float*)d_in[5];
  const float* b1b = (const float*)d_in[6];
  const float* Wa  = (const float*)d_in[7];
  const float* ba  = (const float*)d_in[8];
  const float* Wb  = (const float*)d_in[9];
  const float* bb  = (const float*)d_in[10];
  const float* W2  = (const float*)d_in[11];
  const float* b2  = (const float*)d_in[12];
  short* ws = (short*)d_ws;
  const int B = in_sizes[1];

  hipLaunchKernelGGL(pack_weights_kernel, dim3(904), dim3(256), 0, stream,
                     W1a, W1b, Wa, Wb, ws);
  hipLaunchKernelGGL(geo2vec_kernel, dim3(B / 64), dim3(512), 0, stream,
                     xy, idx, emb, b1a, b1b, ba, bb, W2, b2, ws, (float*)d_out);
}

// Round 16
// 472.473 us; speedup vs baseline: 1.0059x; 1.0059x over previous
//
#include <hip/hip_runtime.h>
#include <hip/hip_bf16.h>

// Geo2Vec fused MLP, bf16 MFMA. Round 16: R15 + hidden barriers.
//  - mid-layer gemm-a (NKT=18) takes the "x is ready" barrier INSIDE its kt
//    loop at i==8 (kt 0-9 read only the immutable xyz region) -> the drain
//    overlaps 8 kts of MFMA work instead of stalling all waves cold.
//  - gemm-b prefetches next gemm-a's kt0 A-frags from xyz during its last kt
//    (xyz never changes) -> no cold A restart after the b->a transition.
//  Hard barriers: 12 (was 21).

typedef __attribute__((ext_vector_type(8))) __bf16 bfv8;
typedef __attribute__((ext_vector_type(8))) short s16x8;
typedef __attribute__((ext_vector_type(4))) float f32x4;
typedef __attribute__((ext_vector_type(4))) int i32x4;

__device__ __forceinline__ short f2bf(float f) {
  unsigned u = __builtin_bit_cast(unsigned, f);
  u = (u + 0x7fffu + ((u >> 16) & 1u)) >> 16;
  return (short)u;
}
__device__ __forceinline__ float bf2f(short s) {
  unsigned u = ((unsigned)(unsigned short)s) << 16;
  return __builtin_bit_cast(float, u);
}
__device__ __forceinline__ int swzaddr(int base, int stride, int row, int colbyte) {
  return base + row * stride + (colbyte ^ (((row & 7) << 4) ^ ((row & 8) << 2)));
}
// LDS-visibility barrier that does NOT drain vmcnt (keeps B prefetch in flight).
__device__ __forceinline__ void ldsbar() {
  __builtin_amdgcn_sched_barrier(0);
  asm volatile("s_waitcnt lgkmcnt(0)");
  __builtin_amdgcn_s_barrier();
  __builtin_amdgcn_sched_barrier(0);
}

// ---------------- weight pack ----------------
// fp32 row-major (K,256) -> bf16 B-frag-major with INTERLEAVED columns:
// packet p = (kt*16 + nt)*64 + lane ; frag col j=lane&15 -> actual col
// n = (nt>>1)*32 + 2*j + (nt&1)   (epilogue cvt_pk un-interleaves)
__global__ void pack_weights_kernel(const float* __restrict__ W1a, const float* __restrict__ W1b,
                                    const float* __restrict__ Wa, const float* __restrict__ Wb,
                                    short* __restrict__ ws) {
  int p = blockIdx.x * blockDim.x + threadIdx.x;
  const int P1 = 10240;           // W1a: 10 kt * 16 nt * 64
  const int P2 = P1 + 8192;       // W1b
  const int P3 = P2 + 8 * 18432;  // Wa
  const int P4 = P3 + 8 * 8192;   // Wb
  if (p >= P4) return;
  const float* src;
  int q;
  if (p < P1)      { src = W1a; q = p; }
  else if (p < P2) { src = W1b; q = p - P1; }
  else if (p < P3) { q = p - P2; int l = q / 18432; q -= l * 18432; src = Wa + l * 147456; }
  else             { q = p - P3; int l = q / 8192;  q -= l * 8192;  src = Wb + l * 65536; }
  const int lane = q & 63, t = q >> 6, nt = t & 15, kt = t >> 4;
  const int k0 = kt * 32 + ((lane >> 4) << 3);
  const int n  = ((nt >> 1) << 5) + ((lane & 15) << 1) + (nt & 1);
  short* dst = ws + (size_t)p * 8;
#pragma unroll
  for (int i = 0; i < 8; ++i) dst[i] = f2bf(src[(size_t)(k0 + i) * 256 + n]);
}

// ---------------- fused MLP ----------------
// LDS (bytes): xyz [0,40960) stride 640 ; x [40960,73728) stride 512 ;
//              t [73728,106496) stride 512
struct BPre { bfv8 b0, b1; };
struct AFrag { bfv8 r0, r1, r2, r3; };
struct Pre { BPre b; AFrag a; };

__device__ __forceinline__ bfv8 bfrag(const short* __restrict__ wp, int kt, int nt, int lane) {
  const short* base = wp + (((size_t)(kt * 16 + nt)) << 9);  // wave-uniform
  return *(const bfv8*)(base + (lane << 3));
}

template<int NKT, int SPLITKT, bool LEAKY, bool MIDBAR, bool PRE_A, bool PRE_NEXT_A>
__device__ __forceinline__ Pre do_gemm(short* lds,
    int a1Base, int a1S, int a2Base, int a2S,
    const short* __restrict__ wp, const short* __restrict__ wpn,
    const float* __restrict__ bias, int outBase,
    int wc, int lane, Pre pre)
{
  const int lo = lane & 15, hi = lane >> 4;
  const int ntb = wc << 1;
  const float2 bv = *(const float2*)(bias + (wc << 5) + (lo << 1));
  f32x4 acc[4][2];
#pragma unroll
  for (int r = 0; r < 4; ++r) { acc[r][0] = (f32x4)0.f; acc[r][1] = (f32x4)0.f; }

  // Decomposed swizzle bases: addr = base[kk&1] + (kk>>1)*128 + rt*(stride*16)
  const int xr  = ((lo & 7) << 4) ^ ((lo & 8) << 2);
  const int hib = hi << 4;
  const char* A1E = (const char*)lds + a1Base + lo * a1S + ((     hib) ^ xr);
  const char* A1O = (const char*)lds + a1Base + lo * a1S + ((64 + hib) ^ xr);
  const char* A2E = (const char*)lds + a2Base + lo * a2S + ((     hib) ^ xr);
  const char* A2O = (const char*)lds + a2Base + lo * a2S + ((64 + hib) ^ xr);

  auto aLoad = [&](int kt, AFrag& dst) {
    const bool g1 = kt < SPLITKT;
    const int kk  = g1 ? kt : kt - SPLITKT;
    const int st  = g1 ? a1S : a2S;
    const char* b = (g1 ? ((kk & 1) ? A1O : A1E) : ((kk & 1) ? A2O : A2E)) + (kk >> 1) * 128;
    dst.r0 = *(const bfv8*)(b);
    dst.r1 = *(const bfv8*)(b + (st << 4));
    dst.r2 = *(const bfv8*)(b + (st << 5));
    dst.r3 = *(const bfv8*)(b + (st << 4) * 3);
  };

  bfv8 bst[4][2];
  AFrag ast[3];
  bst[0][0] = pre.b.b0; bst[0][1] = pre.b.b1;
  if (NKT > 1) { bst[1][0] = bfrag(wp, 1, ntb, lane); bst[1][1] = bfrag(wp, 1, ntb + 1, lane); }
  if (NKT > 2) { bst[2][0] = bfrag(wp, 2, ntb, lane); bst[2][1] = bfrag(wp, 2, ntb + 1, lane); }
  if (PRE_A) ast[0] = pre.a; else aLoad(0, ast[0]);
  if (NKT > 1) aLoad(1, ast[1]);
  Pre nxt;

#pragma unroll
  for (int i = 0; i < NKT; ++i) {
    // hidden barrier: x-region becomes visible here; kt 0..SPLITKT-1 only read xyz
    if (MIDBAR && i == SPLITKT - 2) ldsbar();
    if (i + 3 < NKT) {
      bst[(i + 3) & 3][0] = bfrag(wp, i + 3, ntb, lane);
      bst[(i + 3) & 3][1] = bfrag(wp, i + 3, ntb + 1, lane);
    } else if (i + 3 == NKT || (NKT <= 3 && i == 0)) {  // next gemm's first B frags
      nxt.b.b0 = bfrag(wpn, 0, ntb, lane);
      nxt.b.b1 = bfrag(wpn, 0, ntb + 1, lane);
    }
    if (i + 2 < NKT) aLoad(i + 2, ast[(i + 2) % 3]);
    if (PRE_NEXT_A && i == NKT - 1) {  // next gemm-a's kt0 A-frags (xyz, immutable)
      const char* bx = (const char*)lds + lo * 640 + (hib ^ xr);
      nxt.a.r0 = *(const bfv8*)(bx);
      nxt.a.r1 = *(const bfv8*)(bx + 640 * 16);
      nxt.a.r2 = *(const bfv8*)(bx + 640 * 32);
      nxt.a.r3 = *(const bfv8*)(bx + 640 * 48);
    }
    const AFrag& ac = ast[i % 3];
    __builtin_amdgcn_s_setprio(1);
    acc[0][0] = __builtin_amdgcn_mfma_f32_16x16x32_bf16(ac.r0, bst[i & 3][0], acc[0][0], 0, 0, 0);
    acc[0][1] = __builtin_amdgcn_mfma_f32_16x16x32_bf16(ac.r0, bst[i & 3][1], acc[0][1], 0, 0, 0);
    acc[1][0] = __builtin_amdgcn_mfma_f32_16x16x32_bf16(ac.r1, bst[i & 3][0], acc[1][0], 0, 0, 0);
    acc[1][1] = __builtin_amdgcn_mfma_f32_16x16x32_bf16(ac.r1, bst[i & 3][1], acc[1][1], 0, 0, 0);
    acc[2][0] = __builtin_amdgcn_mfma_f32_16x16x32_bf16(ac.r2, bst[i & 3][0], acc[2][0], 0, 0, 0);
    acc[2][1] = __builtin_amdgcn_mfma_f32_16x16x32_bf16(ac.r2, bst[i & 3][1], acc[2][1], 0, 0, 0);
    acc[3][0] = __builtin_amdgcn_mfma_f32_16x16x32_bf16(ac.r3, bst[i & 3][0], acc[3][0], 0, 0, 0);
    acc[3][1] = __builtin_amdgcn_mfma_f32_16x16x32_bf16(ac.r3, bst[i & 3][1], acc[3][1], 0, 0, 0);
    __builtin_amdgcn_s_setprio(0);
  }
  // epilogue: bias + leaky + cvt_pk(2 bf16) -> one b32 store per pair
#pragma unroll
  for (int rt = 0; rt < 4; ++rt)
#pragma unroll
    for (int rr = 0; rr < 4; ++rr) {
      float v0 = acc[rt][0][rr] + bv.x;
      float v1 = acc[rt][1][rr] + bv.y;
      if (LEAKY) { v0 = fmaxf(v0, 0.01f * v0); v1 = fmaxf(v1, 0.01f * v1); }
      unsigned pk;
      asm("v_cvt_pk_bf16_f32 %0, %1, %2" : "=v"(pk) : "v"(v0), "v"(v1));
      const int orow = (rt << 4) + (hi << 2) + rr;
      *(unsigned*)((char*)lds + swzaddr(outBase, 512, orow, (wc << 6) + (lo << 2))) = pk;
    }
  return nxt;
}

__launch_bounds__(512, 1)
__global__ void geo2vec_kernel(const float* __restrict__ xy, const int* __restrict__ idx,
    const float* __restrict__ emb,
    const float* __restrict__ b1a, const float* __restrict__ b1b,
    const float* __restrict__ ba, const float* __restrict__ bb,
    const float* __restrict__ W2, const float* __restrict__ b2,
    const short* __restrict__ wp, float* __restrict__ out)
{
  __shared__ short lds[53248];  // 104 KB
  const int tid = threadIdx.x;
  const int lane = tid & 63;
  const int wc = __builtin_amdgcn_readfirstlane(tid >> 6);  // wave = col group

  Pre pre;
  pre.b.b0 = bfrag(wp, 0, (wc << 1), lane);
  pre.b.b1 = bfrag(wp, 0, (wc << 1) + 1, lane);

  // ---- prologue: pos-encode + gather z -> xyz tile (64 x 320 bf16) ----
  {
    const int g = tid >> 3, j = tid & 7;  // 8 threads per row
    const int row = blockIdx.x * 64 + g;
    const float xv = xy[2 * row], yv = xy[2 * row + 1];
    const float rv = sqrtf(xv * xv + yv * yv);
    union { short s[8]; i32x4 v; } tmp;
#pragma unroll
    for (int i = 0; i < 8; ++i) {
      const int c = 8 * j + i;
      float fv;
      if (c < 2)       fv = c ? yv : xv;
      else if (c < 22) { int m = c - 2;  float f = 1.0f + (5.0f / 9.0f) * (m >> 1); fv = sinf(((m & 1) ? yv : xv) * f); }
      else if (c < 42) { int m = c - 22; float f = 1.0f + (5.0f / 9.0f) * (m >> 1); fv = cosf(((m & 1) ? yv : xv) * f); }
      else if (c < 44) fv = (c == 42) ? xv : yv;
      else if (c < 54) fv = sinf(rv * (1.0f + (5.0f / 9.0f) * (c - 44)));
      else             fv = cosf(rv * (1.0f + (5.0f / 9.0f) * (c - 54)));
      tmp.s[i] = f2bf(fv);
    }
    *(i32x4*)((char*)lds + swzaddr(0, 640, g, j << 4)) = tmp.v;
    const float* zr = emb + (size_t)(unsigned)idx[row] * 256;
#pragma unroll
    for (int c4 = 0; c4 < 4; ++c4) {
      const int cel = j * 32 + c4 * 8;
      const float4 f0 = *(const float4*)(zr + cel);
      const float4 f1 = *(const float4*)(zr + cel + 4);
      union { short s[8]; i32x4 v; } t2;
      t2.s[0] = f2bf(f0.x); t2.s[1] = f2bf(f0.y); t2.s[2] = f2bf(f0.z); t2.s[3] = f2bf(f0.w);
      t2.s[4] = f2bf(f1.x); t2.s[5] = f2bf(f1.y); t2.s[6] = f2bf(f1.z); t2.s[7] = f2bf(f1.w);
      *(i32x4*)((char*)lds + swzaddr(0, 640, g, (64 + cel) << 1)) = t2.v;
    }
  }
  ldsbar();

  // layer 1: a writes t; hard bar; b reads t, writes x (prefetches a(0)'s A)
  pre = do_gemm<10, 10, true,  false, false, false>(lds, 0, 640, 0, 640,
        wp, wp + 81920, b1a, 73728, wc, lane, pre);
  ldsbar();
  pre = do_gemm<8, 8, false, false, false, true>(lds, 73728, 512, 73728, 512,
        wp + 81920, wp + 147456, b1b, 40960, wc, lane, pre);
  // NO barrier here: mid-layer gemm-a carries it inside (MIDBAR)
  for (int l = 0; l < 8; ++l) {
    const short* wa = wp + 147456 + l * 147456;
    const short* wb = wp + 1327104 + l * 65536;
    const short* wan = (l < 7) ? (wa + 147456) : wp;  // dummy (valid mem) on last layer
    pre = do_gemm<18, 10, true, true, true, false>(lds, 0, 640, 40960, 512,
          wa, wb, ba + l * 256, 73728, wc, lane, pre);
    ldsbar();  // t ready (hard)
    pre = do_gemm<8, 8, false, false, false, true>(lds, 73728, 512, 73728, 512,
          wb, wan, bb + l * 256, 40960, wc, lane, pre);
    // no trailing barrier: next a's MIDBAR (or the final ldsbar below) covers it
  }
  ldsbar();  // x ready for the final reduce

  // final: out = x @ W2 + b2 ; 8 threads per row (32 cols each), width-8 reduce
  {
    const int r = tid >> 3, j = tid & 7;
    float sum = 0.f;
#pragma unroll
    for (int h = 0; h < 4; ++h) {
      const int cb = 64 * j + 16 * h;
      const s16x8 v = *(const s16x8*)((const char*)lds + swzaddr(40960, 512, r, cb));
      const int c0 = 32 * j + 8 * h;
      const float4 w0 = *(const float4*)(W2 + c0);
      const float4 w1 = *(const float4*)(W2 + c0 + 4);
      sum += bf2f(v[0]) * w0.x + bf2f(v[1]) * w0.y + bf2f(v[2]) * w0.z + bf2f(v[3]) * w0.w;
      sum += bf2f(v[4]) * w1.x + bf2f(v[5]) * w1.y + bf2f(v[6]) * w1.z + bf2f(v[7]) * w1.w;
    }
    sum += __shfl_xor(sum, 1); sum += __shfl_xor(sum, 2); sum += __shfl_xor(sum, 4);
    if (j == 0) out[blockIdx.x * 64 + r] = sum + b2[0];
  }
}

extern "C" void kernel_launch(void* const* d_in, const int* in_sizes, int n_in,
                              void* d_out, int out_size, void* d_ws, size_t ws_size,
                              hipStream_t stream) {
  const float* xy  = (const float*)d_in[0];
  const int*   idx = (const int*)d_in[1];
  const float* emb = (const float*)d_in[2];
  const float* W1a = (const float*)d_in[3];
  const float* b1a = (const float*)d_in[4];
  const float* W1b = (const float*)d_in[5];
  const float* b1b = (const float*)d_in[6];
  const float* Wa  = (const float*)d_in[7];
  const float* ba  = (const float*)d_in[8];
  const float* Wb  = (const float*)d_in[9];
  const float* bb  = (const float*)d_in[10];
  const float* W2  = (const float*)d_in[11];
  const float* b2  = (const float*)d_in[12];
  short* ws = (short*)d_ws;
  const int B = in_sizes[1];

  hipLaunchKernelGGL(pack_weights_kernel, dim3(904), dim3(256), 0, stream,
                     W1a, W1b, Wa, Wb, ws);
  hipLaunchKernelGGL(geo2vec_kernel, dim3(B / 64), dim3(512), 0, stream,
                     xy, idx, emb, b1a, b1b, ba, bb, W2, b2, ws, (float*)d_out);
}